// Round 1
// baseline (114.472 us; speedup 1.0000x reference)
//
#include <hip/hip_runtime.h>

// SSIM loss, fully fused: channel-mean + separable 11x11 Gaussian convs
// (horizontal in LDS, vertical in a per-thread register ring) + SSIM map +
// global mean reduction. One pass over HBM.

constexpr int KW   = 11;
constexpr int HALF = 5;
constexpr int TC   = 256;   // tile cols = block size
constexpr int TR   = 64;    // tile rows per block
constexpr int IMG_H = 512;
constexpr int IMG_W = 512;
constexpr int NB   = 32;    // batch
constexpr int NCH  = 3;
constexpr int LW   = TC + 2 * HALF;   // 266 lds row width

__global__ __launch_bounds__(TC)
void ssim_fused(const float* __restrict__ pred,
                const float* __restrict__ targ,
                const float* __restrict__ win,
                float* __restrict__ out)
{
    __shared__ float lP[2][LW];
    __shared__ float lT[2][LW];
    __shared__ float red[4];

    const int tid = threadIdx.x;
    int bid = blockIdx.x;
    const int ncol = IMG_W / TC;          // 2
    const int nrow = IMG_H / TR;          // 8
    const int cb = bid % ncol; bid /= ncol;
    const int rb = bid % nrow; bid /= nrow;
    const int img = bid;                  // 0..31
    const int C0 = cb * TC;
    const int R0 = rb * TR;

    // exact 1-D gaussian from the passed window: w[i][j] = g[i]*g[j]
    float g[KW];
    {
        float g5 = sqrtf(win[HALF * KW + HALF]);
        #pragma unroll
        for (int j = 0; j < KW; ++j) g[j] = win[HALF * KW + j] / g5;
    }

    const size_t ims = (size_t)IMG_H * IMG_W;
    const float* pb = pred + (size_t)img * NCH * ims;
    const float* tb = targ + (size_t)img * NCH * ims;

    // vertical register ring: rows r-10..r in slots 0..10
    float hP[KW], hT[KW], hP2[KW], hT2[KW], hPT[KW];
    #pragma unroll
    for (int j = 0; j < KW; ++j) { hP[j]=0.f; hT[j]=0.f; hP2[j]=0.f; hT2[j]=0.f; hPT[j]=0.f; }

    const float inv3 = 1.0f / 3.0f;
    const float C1 = 1e-4f;    // 0.01^2
    const float C2 = 9e-4f;    // 0.03^2

    const int col0 = C0 - HALF + tid;       // lds slot tid
    const int col1 = col0 + TC;             // lds slot tid+TC (tid < LW-TC)
    const bool has2 = (tid < LW - TC);

    float p0 = 0.f, t0 = 0.f, p1 = 0.f, t1 = 0.f;  // prefetched row values

    auto loadrow = [&](int r, float& P0, float& T0, float& P1, float& T1) {
        P0 = 0.f; T0 = 0.f; P1 = 0.f; T1 = 0.f;
        if (r >= 0 && r < IMG_H) {
            if (col0 >= 0 && col0 < IMG_W) {
                size_t a = (size_t)r * IMG_W + col0;
                P0 = (pb[a] + pb[a + ims] + pb[a + 2 * ims]) * inv3;
                T0 = (tb[a] + tb[a + ims] + tb[a + 2 * ims]) * inv3;
            }
            if (has2 && col1 >= 0 && col1 < IMG_W) {
                size_t a = (size_t)r * IMG_W + col1;
                P1 = (pb[a] + pb[a + ims] + pb[a + 2 * ims]) * inv3;
                T1 = (tb[a] + tb[a + ims] + tb[a + 2 * ims]) * inv3;
            }
        }
    };

    loadrow(R0 - HALF, p0, t0, p1, t1);

    float acc = 0.f;

    for (int it = 0; it < TR + 2 * HALF; ++it) {
        const int r = R0 - HALF + it;
        const int buf = it & 1;
        lP[buf][tid] = p0;
        lT[buf][tid] = t0;
        if (has2) { lP[buf][tid + TC] = p1; lT[buf][tid + TC] = t1; }
        // prefetch next row (issued before barrier; completes under compute)
        loadrow(r + 1, p0, t0, p1, t1);
        __syncthreads();

        // horizontal 11-tap pass (stride-1 LDS reads, conflict-free)
        float sP = 0.f, sT = 0.f, sP2 = 0.f, sT2 = 0.f, sPT = 0.f;
        #pragma unroll
        for (int j = 0; j < KW; ++j) {
            float w = g[j];
            float p = lP[buf][tid + j];
            float t = lT[buf][tid + j];
            sP  += w * p;      sT  += w * t;
            sP2 += w * p * p;  sT2 += w * t * t;  sPT += w * p * t;
        }
        // push into register ring (static indices only)
        #pragma unroll
        for (int k = 0; k < KW - 1; ++k) {
            hP[k]=hP[k+1]; hT[k]=hT[k+1]; hP2[k]=hP2[k+1]; hT2[k]=hT2[k+1]; hPT[k]=hPT[k+1];
        }
        hP[KW-1]=sP; hT[KW-1]=sT; hP2[KW-1]=sP2; hT2[KW-1]=sT2; hPT[KW-1]=sPT;

        // vertical 11-tap pass from registers, then SSIM
        if (it >= 2 * HALF) {
            float mu1=0.f, mu2=0.f, ep2=0.f, et2=0.f, ept=0.f;
            #pragma unroll
            for (int k = 0; k < KW; ++k) {
                float w = g[k];
                mu1 += w * hP[k];  mu2 += w * hT[k];
                ep2 += w * hP2[k]; et2 += w * hT2[k]; ept += w * hPT[k];
            }
            float m11 = mu1 * mu1, m22 = mu2 * mu2, m12 = mu1 * mu2;
            float s1 = ep2 - m11, s2 = et2 - m22, s12 = ept - m12;
            float num = (2.f * m12 + C1) * (2.f * s12 + C2);
            float den = (m11 + m22 + C1) * (s1 + s2 + C2);
            acc += 1.f - num / den;
        }
    }

    // block reduction: wave shuffle then cross-wave via LDS
    #pragma unroll
    for (int off = 32; off >= 1; off >>= 1)
        acc += __shfl_down(acc, off, 64);
    const int wid  = tid >> 6;
    const int lane = tid & 63;
    if (lane == 0) red[wid] = acc;
    __syncthreads();
    if (tid == 0) {
        float s = red[0] + red[1] + red[2] + red[3];
        atomicAdd(out, s * (1.0f / (float)(NB * IMG_H * IMG_W)));
    }
}

extern "C" void kernel_launch(void* const* d_in, const int* in_sizes, int n_in,
                              void* d_out, int out_size, void* d_ws, size_t ws_size,
                              hipStream_t stream) {
    const float* pred = (const float*)d_in[0];
    const float* targ = (const float*)d_in[1];
    const float* win  = (const float*)d_in[2];
    float* out = (float*)d_out;

    hipMemsetAsync(out, 0, sizeof(float), stream);

    dim3 grid(NB * (IMG_H / TR) * (IMG_W / TC));   // 32*8*2 = 512 blocks
    ssim_fused<<<grid, TC, 0, stream>>>(pred, targ, win, out);
}